// Round 6
// baseline (447.507 us; speedup 1.0000x reference)
//
#include <hip/hip_runtime.h>

// spectralAgg: per-(batch,patch) DANet channel attention, 8x8 grid of 64x64
// patches of (8,64,512,512) fp32.
// E = p p^T (split-bf16: G + S + S^T, S = hi*lo^T), A = softmax(-E) (gamma
// folded), out = A p (bf16 MFMA).
// R6: depth-2 register prefetch (memory queue never empties), R4-style XOR
// swizzled phase-3 tile (conflict-free), XCD co-location of row-sharing WGs.

#define NW   512
#define HWs  262144
#define NS   16           // stages per phase: tile = 4 patch rows = 256 i

typedef __attribute__((ext_vector_type(8)))  __bf16 bf8;
typedef __attribute__((ext_vector_type(4)))  __bf16 bf4;
typedef __attribute__((ext_vector_type(16))) float  f32x16;

#define F4E(v,j) ((j)==0?(v).x:(j)==1?(v).y:(j)==2?(v).z:(v).w)

// barrier waiting only LDS ops: global prefetch stays in flight across it
__device__ __forceinline__ void bar_lgkm() {
  asm volatile("s_waitcnt lgkmcnt(0)" ::: "memory");
  __builtin_amdgcn_s_barrier();
}

__device__ __forceinline__ void load1(const float* xp, int wv8, int g2, int e16,
                                      int st, float4 (&R)[8]) {
#pragma unroll
  for (int k = 0; k < 8; ++k)
    R[k] = *(const float4*)(xp + (size_t)(k*8+wv8)*HWs + (size_t)(st*4+g2)*NW + e16*4);
}

__device__ __forceinline__ void cvt1(char* sH, char* sL, int wv8, int g2, int e16,
                                     const float4 (&R)[8]) {
#pragma unroll
  for (int k = 0; k < 8; ++k) {
    const int c = k*8 + wv8;
    const float4 v = R[k];
    bf4 h, lo;
    h[0]=(__bf16)v.x; h[1]=(__bf16)v.y; h[2]=(__bf16)v.z; h[3]=(__bf16)v.w;
    lo[0]=(__bf16)(v.x-(float)h[0]); lo[1]=(__bf16)(v.y-(float)h[1]);
    lo[2]=(__bf16)(v.z-(float)h[2]); lo[3]=(__bf16)(v.w-(float)h[3]);
    const int off = c*512 + ((g2*128 + e16*8) ^ ((c&15)<<4));
    *(bf4*)(sH+off) = h;
    *(bf4*)(sL+off) = lo;
  }
}

__device__ __forceinline__ void mfma1(const char* pA, const char* pBh, const char* pBl,
                                      int hh, int swz1, f32x16& accG, f32x16& accS) {
#pragma unroll
  for (int k0 = 0; k0 < 8; ++k0) {
    const int off = (k0*32 + hh*16) ^ swz1;
    const bf8 a  = *(const bf8*)(pA  + off);
    const bf8 bh = *(const bf8*)(pBh + off);
    const bf8 bl = *(const bf8*)(pBl + off);
    accG = __builtin_amdgcn_mfma_f32_32x32x16_bf16(a, bh, accG, 0, 0, 0);
    accS = __builtin_amdgcn_mfma_f32_32x32x16_bf16(a, bl, accS, 0, 0, 0);
  }
}

__device__ __forceinline__ void load3(const float* xp, int quad, int rwb, int e16,
                                      int st, float4 (&R)[8]) {
#pragma unroll
  for (int k = 0; k < 8; ++k) {
    const int cc = k & 3, mm = k >> 2;
    R[k] = *(const float4*)(xp + (size_t)(quad*4+cc)*HWs + (size_t)(st*4+rwb+mm*2)*NW + e16*4);
  }
}

__device__ __forceinline__ void cvt3(char* sT, int quad, int rwb, int e16,
                                     const float4 (&R)[8]) {
#pragma unroll
  for (int mm = 0; mm < 2; ++mm) {
    const int row = rwb + mm*2;
#pragma unroll
    for (int jj = 0; jj < 4; ++jj) {
      const int i = row*64 + e16*4 + jj;
      bf4 qv;
      qv[0] = (__bf16)F4E(R[mm*4+0], jj);
      qv[1] = (__bf16)F4E(R[mm*4+1], jj);
      qv[2] = (__bf16)F4E(R[mm*4+2], jj);
      qv[3] = (__bf16)F4E(R[mm*4+3], jj);
      const int sw = ((i & 15) ^ ((i >> 4) & 7)) << 4;
      *(bf4*)(sT + (i & 127)*256 + ((((i >> 7)*128) + quad*8) ^ sw)) = qv;
    }
  }
}

extern "C" __global__ __launch_bounds__(512, 4)
void spectralAgg_kernel(const float* __restrict__ x, const float* __restrict__ g,
                        float* __restrict__ out) {
  __shared__ char lds[65536];
  char* sH = lds;            // P1: hi stage 32KB [64c][512B]; later E_lds 16KB / sT 32KB
  char* sL = lds + 32768;    // P1: lo stage 32KB; later S_lds 16KB
  char* sA = lds + 49152;    // attention bf16 [64c][256B], swizzled (16KB)

  const int T   = threadIdx.x;
  const int wv8 = T >> 6;
  const int l   = T & 63;
  const int l31 = l & 31;
  const int hh  = l >> 5;
  const int g2  = (T >> 4) & 3;
  const int e16 = T & 15;

  // XCD co-location: the 8 WGs covering one image-row band (pc=0..7 of a given
  // (b,pr)) get blockIdx differing by 64 -> same residue mod 8 -> same XCD.
  const int id = blockIdx.x;
  const int pc  = id >> 6;
  const int rem = id & 63;
  const int b   = rem >> 3;
  const int pr  = rem & 7;
  const size_t pbase = (size_t)b*64*HWs + (size_t)(pr*64)*NW + (size_t)(pc*64);
  const float* xp = x + pbase;
  float* op = out + pbase;

  // ================= Phase 1: Gram via split-bf16 MFMA (K-split waves) ======
  const int q  = wv8 & 3;          // quadrant of E
  const int kh = wv8 >> 2;         // K-half
  const int ct = q >> 1, dt = q & 1;
  const char* pA  = sH + (size_t)(ct*32+l31)*512 + kh*256;
  const char* pBh = sH + (size_t)(dt*32+l31)*512 + kh*256;
  const char* pBl = sL + (size_t)(dt*32+l31)*512 + kh*256;
  const int swz1 = (l31 & 15) << 4;

  f32x16 accG, accS;
#pragma unroll
  for (int r = 0; r < 16; ++r) { accG[r] = 0.f; accS[r] = 0.f; }

  float4 rA[8], rB[8];
  load1(xp, wv8, g2, e16, 0, rA);
  load1(xp, wv8, g2, e16, 1, rB);

  for (int st = 0; st < NS; st += 2) {
    cvt1(sH, sL, wv8, g2, e16, rA);            // waits rA (issued 2 stages ago)
    if (st + 2 < NS) load1(xp, wv8, g2, e16, st + 2, rA);
    bar_lgkm();
    mfma1(pA, pBh, pBl, hh, swz1, accG, accS);
    bar_lgkm();

    cvt1(sH, sL, wv8, g2, e16, rB);
    if (st + 3 < NS) load1(xp, wv8, g2, e16, st + 3, rB);
    bar_lgkm();
    mfma1(pA, pBh, pBl, hh, swz1, accG, accS);
    bar_lgkm();
  }

  // ---- E = G + S + S^T, reduced over K-halves (LDS overlays) ----
  float* E_lds = (float*)sH;       // 16KB [64][64]
  float* S_lds = (float*)sL;       // 16KB [64][64]
  if (kh == 0) {
#pragma unroll
    for (int r = 0; r < 16; ++r) {
      const int cr = ct*32 + (r&3) + ((r>>2)<<3) + (hh<<2);
      const int d  = dt*32 + l31;
      S_lds[cr*64+d] = accS[r];
      E_lds[cr*64+d] = accG[r] + accS[r];
    }
  }
  bar_lgkm();
  if (kh == 1) {
#pragma unroll
    for (int r = 0; r < 16; ++r) {
      const int cr = ct*32 + (r&3) + ((r>>2)<<3) + (hh<<2);
      const int d  = dt*32 + l31;
      S_lds[cr*64+d] += accS[r];
      E_lds[cr*64+d] += accG[r] + accS[r];
    }
  }
  bar_lgkm();
#pragma unroll
  for (int r = 0; r < 8; ++r) {    // E += S^T
    const int c = T >> 3, d = (T&7)*8 + r;
    E_lds[c*64+d] += S_lds[d*64+c];
  }
  bar_lgkm();

  // ============ Phase 2: softmax(-E) -> sA; phase-3 stages 0,1 prefetched ===
  const int quad = (wv8*4+g2) & 15;
  const int rwb  = (wv8*4+g2) >> 4;
  load3(xp, quad, rwb, e16, 0, rA);
  load3(xp, quad, rwb, e16, 1, rB);

  const float gs = 1.0f + g[0];
#pragma unroll 1
  for (int rr = 0; rr < 8; ++rr) {
    const int c = wv8*8 + rr;
    const float e = E_lds[c*64 + l];
    float mn = e;
#pragma unroll
    for (int o = 32; o; o >>= 1) mn = fminf(mn, __shfl_xor(mn, o));
    const float w = __expf(mn - e);
    float s = w;
#pragma unroll
    for (int o = 32; o; o >>= 1) s += __shfl_xor(s, o);
    const float a = gs * w / s;
    *(__bf16*)(sA + c*256 + ((l*2) ^ ((c&15)<<4))) = (__bf16)a;
  }
  bar_lgkm();

  // ================= Phase 3: O^T[i][c] = sum_d p[d][i] A[c][d] =============
  char* sT = sH;                   // [128 rows][256B], XOR swizzled (32KB)
  const int i3  = wv8*32 + l31;
  const char* pP = sT + (size_t)(i3 & 127) * 256;
  const int hb3 = (i3 >> 7) * 128;
  const int sw3 = ((i3 & 15) ^ ((i3 >> 4) & 7)) << 4;

  // B-fragments (attention) are stage-invariant: hoist into registers.
  bf8 bfr[2][4];
#pragma unroll
  for (int c2 = 0; c2 < 2; ++c2)
#pragma unroll
    for (int k0 = 0; k0 < 4; ++k0)
      bfr[c2][k0] = *(const bf8*)(sA + (size_t)(c2*32+l31)*256 +
                                  ((k0*32 + hh*16) ^ ((l31&15)<<4)));

  for (int st = 0; st < NS; st += 2) {
    // ---- even stage: consume rA ----
    cvt3(sT, quad, rwb, e16, rA);
    if (st + 2 < NS) load3(xp, quad, rwb, e16, st + 2, rA);
    bar_lgkm();
    {
      f32x16 oo0, oo1;
#pragma unroll
      for (int r = 0; r < 16; ++r) { oo0[r] = 0.f; oo1[r] = 0.f; }
#pragma unroll
      for (int k0 = 0; k0 < 4; ++k0) {
        const bf8 pa = *(const bf8*)(pP + ((hb3 + k0*32 + hh*16) ^ sw3));
        oo0 = __builtin_amdgcn_mfma_f32_32x32x16_bf16(pa, bfr[0][k0], oo0, 0, 0, 0);
        oo1 = __builtin_amdgcn_mfma_f32_32x32x16_bf16(pa, bfr[1][k0], oo1, 0, 0, 0);
      }
#pragma unroll
      for (int rq = 0; rq < 4; ++rq) {
        const int iloc = wv8*32 + rq*8 + hh*4;
        const int gi = st*256 + iloc;
        float* oprow = op + (size_t)(gi >> 6)*NW + (gi & 63);
        float4 q0; q0.x=oo0[rq*4+0]; q0.y=oo0[rq*4+1]; q0.z=oo0[rq*4+2]; q0.w=oo0[rq*4+3];
        *(float4*)(oprow + (size_t)l31*HWs) = q0;
        float4 q1; q1.x=oo1[rq*4+0]; q1.y=oo1[rq*4+1]; q1.z=oo1[rq*4+2]; q1.w=oo1[rq*4+3];
        *(float4*)(oprow + (size_t)(32+l31)*HWs) = q1;
      }
    }
    bar_lgkm();

    // ---- odd stage: consume rB ----
    cvt3(sT, quad, rwb, e16, rB);
    if (st + 3 < NS) load3(xp, quad, rwb, e16, st + 3, rB);
    bar_lgkm();
    {
      f32x16 oo0, oo1;
#pragma unroll
      for (int r = 0; r < 16; ++r) { oo0[r] = 0.f; oo1[r] = 0.f; }
#pragma unroll
      for (int k0 = 0; k0 < 4; ++k0) {
        const bf8 pa = *(const bf8*)(pP + ((hb3 + k0*32 + hh*16) ^ sw3));
        oo0 = __builtin_amdgcn_mfma_f32_32x32x16_bf16(pa, bfr[0][k0], oo0, 0, 0, 0);
        oo1 = __builtin_amdgcn_mfma_f32_32x32x16_bf16(pa, bfr[1][k0], oo1, 0, 0, 0);
      }
#pragma unroll
      for (int rq = 0; rq < 4; ++rq) {
        const int iloc = wv8*32 + rq*8 + hh*4;
        const int gi = (st+1)*256 + iloc;
        float* oprow = op + (size_t)(gi >> 6)*NW + (gi & 63);
        float4 q0; q0.x=oo0[rq*4+0]; q0.y=oo0[rq*4+1]; q0.z=oo0[rq*4+2]; q0.w=oo0[rq*4+3];
        *(float4*)(oprow + (size_t)l31*HWs) = q0;
        float4 q1; q1.x=oo1[rq*4+0]; q1.y=oo1[rq*4+1]; q1.z=oo1[rq*4+2]; q1.w=oo1[rq*4+3];
        *(float4*)(oprow + (size_t)(32+l31)*HWs) = q1;
      }
    }
    bar_lgkm();
  }
}

extern "C" void kernel_launch(void* const* d_in, const int* in_sizes, int n_in,
                              void* d_out, int out_size, void* d_ws, size_t ws_size,
                              hipStream_t stream) {
  const float* x = (const float*)d_in[0];
  const float* g = (const float*)d_in[1];
  float* o = (float*)d_out;
  spectralAgg_kernel<<<dim3(512), dim3(512), 0, stream>>>(x, g, o);
}

// Round 7
// 412.477 us; speedup vs baseline: 1.0849x; 1.0849x over previous
//
#include <hip/hip_runtime.h>

// spectralAgg R7: 3-kernel row-band-coalesced pipeline.
//  K1: partial Gram per (b,pr,hq) slice  -> d_ws Epart[pat][hq][64][64] f32
//  K2: reduce + softmax(-E) (gamma folded) -> d_ws A[pat][64][64] bf16
//  K3: PV (out = A p) per (b,pr,hq) slice, LDS-bounce transpose
// All global reads/writes of x/out are 1KB-per-instruction contiguous runs
// (2KB per (c,h) row across wave pairs) to test the DRAM-granularity theory.
// Falls back to the proven R4 monolithic kernel if ws_size < 36MB.

#define NW  512
#define HWs 262144

typedef __attribute__((ext_vector_type(4)))  __bf16 bf4;
typedef __attribute__((ext_vector_type(8)))  __bf16 bf8;
typedef __attribute__((ext_vector_type(16))) float  f32x16;

#define MFMA __builtin_amdgcn_mfma_f32_32x32x16_bf16
#define F4E(v,j) ((j)==0?(v).x:(j)==1?(v).y:(j)==2?(v).z:(v).w)

// barrier waiting only LDS ops: global prefetch stays in flight across it
__device__ __forceinline__ void bar_lgkm() {
  asm volatile("s_waitcnt lgkmcnt(0)" ::: "memory");
  __builtin_amdgcn_s_barrier();
}

// natural-stage [64 c][1024B] XOR-swizzled byte offset; rb = byte offset in row
__device__ __forceinline__ int soff(int c, int rb) {
  return c * 1024 + (rb & 512) + ((rb & 511) ^ ((c & 31) << 4));
}

// ======================= K1: partial Gram =======================
extern "C" __global__ __launch_bounds__(512, 2)
void k1_gram(const float* __restrict__ x, float* __restrict__ ep) {
  __shared__ char lds[133120];
  char* sHi = lds;                     // [64][1024B]
  char* sLo = lds + 65536;
  float* S_lds = (float*)lds;          // overlay after K-loop: [8 pc][64*65]

  const int t   = threadIdx.x;
  const int w8  = t >> 6;              // wave = patch pc
  const int l   = t & 63;
  const int l31 = l & 31, hh = l >> 5;
  const int pc  = w8;
  const int cld = t >> 7;              // 0..3
  const int hf  = (t >> 6) & 1;

  const int bid = blockIdx.x;          // 256 = b*32 + pr*4 + hq
  const int b  = bid >> 5;
  const int pr = (bid >> 2) & 7;
  const int hq = bid & 3;
  const float* xb = x + (size_t)b * 64 * HWs + (size_t)(pr * 64 + hq * 16) * NW
                  + hf * 256 + l * 4;

  f32x16 aG00, aG01, aG10, aG11, aS00, aS01, aS10, aS11;
#pragma unroll
  for (int i = 0; i < 16; ++i) {
    aG00[i]=0.f; aG01[i]=0.f; aG10[i]=0.f; aG11[i]=0.f;
    aS00[i]=0.f; aS01[i]=0.f; aS10[i]=0.f; aS11[i]=0.f;
  }

  float4 ra[16];
#pragma unroll
  for (int j = 0; j < 16; ++j)
    ra[j] = *(const float4*)(xb + (size_t)(j * 4 + cld) * HWs);

  for (int r = 0; r < 16; ++r) {
    // convert + stage hi/lo (2-way write conflicts = free)
#pragma unroll
    for (int j = 0; j < 16; ++j) {
      const int c = j * 4 + cld;
      const float4 v = ra[j];
      bf4 h, lo;
      h[0]=(__bf16)v.x; h[1]=(__bf16)v.y; h[2]=(__bf16)v.z; h[3]=(__bf16)v.w;
      lo[0]=(__bf16)(v.x-(float)h[0]); lo[1]=(__bf16)(v.y-(float)h[1]);
      lo[2]=(__bf16)(v.z-(float)h[2]); lo[3]=(__bf16)(v.w-(float)h[3]);
      const int wb = c * 1024 + hf * 512 + ((l * 8) ^ ((c & 31) << 4));
      *(bf4*)(sHi + wb) = h;
      *(bf4*)(sLo + wb) = lo;
    }
    if (r + 1 < 16) {
#pragma unroll
      for (int j = 0; j < 16; ++j)
        ra[j] = *(const float4*)(xb + (size_t)(j * 4 + cld) * HWs
                                 + (size_t)(r + 1) * NW);
    }
    bar_lgkm();
#pragma unroll
    for (int ks = 0; ks < 4; ++ks) {
      const int rb = pc * 128 + ks * 32 + hh * 16;
      const bf8 a0 = *(const bf8*)(sHi + soff(l31, rb));       // hi rows 0..31
      const bf8 a1 = *(const bf8*)(sHi + soff(32 + l31, rb));  // hi rows 32..63
      const bf8 q0 = *(const bf8*)(sLo + soff(l31, rb));
      const bf8 q1 = *(const bf8*)(sLo + soff(32 + l31, rb));
      aG00 = MFMA(a0, a0, aG00, 0, 0, 0);
      aG01 = MFMA(a0, a1, aG01, 0, 0, 0);
      aG10 = MFMA(a1, a0, aG10, 0, 0, 0);
      aG11 = MFMA(a1, a1, aG11, 0, 0, 0);
      aS00 = MFMA(a0, q0, aS00, 0, 0, 0);
      aS01 = MFMA(a0, q1, aS01, 0, 0, 0);
      aS10 = MFMA(a1, q0, aS10, 0, 0, 0);
      aS11 = MFMA(a1, q1, aS11, 0, 0, 0);
    }
    bar_lgkm();
  }

  // S -> LDS (overlay stage; all MFMA reads done), then P = G + S + S^T
#pragma unroll
  for (int i = 0; i < 16; ++i) {
    const int rr = (i & 3) + ((i >> 2) << 3) + (hh << 2);
    S_lds[pc * 4160 + (rr)      * 65 + l31]      = aS00[i];
    S_lds[pc * 4160 + (rr)      * 65 + 32 + l31] = aS01[i];
    S_lds[pc * 4160 + (32 + rr) * 65 + l31]      = aS10[i];
    S_lds[pc * 4160 + (32 + rr) * 65 + 32 + l31] = aS11[i];
  }
  bar_lgkm();
  const int pat = b * 64 + pr * 8 + pc;
  float* epb = ep + ((size_t)(pat * 4 + hq) << 12);
#pragma unroll
  for (int i = 0; i < 16; ++i) {
    const int rr = (i & 3) + ((i >> 2) << 3) + (hh << 2);
    epb[(rr)      * 64 + l31]      = aG00[i] + aS00[i] + S_lds[pc*4160 + (l31)    *65 + rr];
    epb[(rr)      * 64 + 32 + l31] = aG01[i] + aS01[i] + S_lds[pc*4160 + (32+l31) *65 + rr];
    epb[(32 + rr) * 64 + l31]      = aG10[i] + aS10[i] + S_lds[pc*4160 + (l31)    *65 + 32 + rr];
    epb[(32 + rr) * 64 + 32 + l31] = aG11[i] + aS11[i] + S_lds[pc*4160 + (32+l31) *65 + 32 + rr];
  }
}

// ======================= K2: reduce + softmax =======================
extern "C" __global__ __launch_bounds__(256)
void k2_softmax(const float* __restrict__ ep, const float* __restrict__ g,
                __bf16* __restrict__ attn) {
  const int pat = blockIdx.x;
  const int w4 = threadIdx.x >> 6, l = threadIdx.x & 63;
  const float gs = 1.0f + g[0];
  const float* e0 = ep + ((size_t)(pat * 4) << 12);
#pragma unroll 1
  for (int cc = 0; cc < 16; ++cc) {
    const int c = w4 * 16 + cc;
    const int o = c * 64 + l;
    const float e = e0[o] + e0[4096 + o] + e0[8192 + o] + e0[12288 + o];
    float mn = e;
#pragma unroll
    for (int off = 32; off; off >>= 1) mn = fminf(mn, __shfl_xor(mn, off));
    const float w = __expf(mn - e);
    float s = w;
#pragma unroll
    for (int off = 32; off; off >>= 1) s += __shfl_xor(s, off);
    attn[(size_t)pat * 4096 + o] = (__bf16)(gs * w / s);
  }
}

// ======================= K3: PV =======================
extern "C" __global__ __launch_bounds__(512, 2)
void k3_pv(const float* __restrict__ x, const __bf16* __restrict__ attn,
           float* __restrict__ out) {
  __shared__ char lds[139264];
  char* nat = lds;                 // [64 c][1024B] swizzled natural hi stage
  char* pT  = lds + 65536;         // [512 i][144B] transposed (i rows, d cols)

  const int t   = threadIdx.x;
  const int w8  = t >> 6;
  const int l   = t & 63;
  const int l31 = l & 31, hh = l >> 5;
  const int pc  = w8;
  const int cld = t >> 7;
  const int hf  = (t >> 6) & 1;
  const int cb  = t & 15;          // bounce c-block
  const int wb0 = t >> 4;          // bounce w-block base (0..31)

  const int bid = blockIdx.x;
  const int b  = bid >> 5;
  const int pr = (bid >> 2) & 7;
  const int hq = bid & 3;
  const float* xb = x + (size_t)b * 64 * HWs + (size_t)(pr * 64 + hq * 16) * NW
                  + hf * 256 + l * 4;
  float* ob = out + (size_t)b * 64 * HWs + (size_t)(pr * 64 + hq * 16) * NW;
  const int pat = b * 64 + pr * 8 + pc;

  // attention B-fragments from global (stage-invariant)
  bf8 af0[4], af1[4];
#pragma unroll
  for (int ks = 0; ks < 4; ++ks) {
    af0[ks] = *(const bf8*)(attn + (size_t)pat * 4096 + (l31)      * 64 + ks * 16 + hh * 8);
    af1[ks] = *(const bf8*)(attn + (size_t)pat * 4096 + (32 + l31) * 64 + ks * 16 + hh * 8);
  }

  float4 ra[16];
#pragma unroll
  for (int j = 0; j < 16; ++j)
    ra[j] = *(const float4*)(xb + (size_t)(j * 4 + cld) * HWs);

  for (int r = 0; r < 16; ++r) {
    // stage natural hi
#pragma unroll
    for (int j = 0; j < 16; ++j) {
      const int c = j * 4 + cld;
      const float4 v = ra[j];
      bf4 h;
      h[0]=(__bf16)v.x; h[1]=(__bf16)v.y; h[2]=(__bf16)v.z; h[3]=(__bf16)v.w;
      *(bf4*)(nat + c * 1024 + hf * 512 + ((l * 8) ^ ((c & 31) << 4))) = h;
    }
    if (r + 1 < 16) {
#pragma unroll
      for (int j = 0; j < 16; ++j)
        ra[j] = *(const float4*)(xb + (size_t)(j * 4 + cld) * HWs
                                 + (size_t)(r + 1) * NW);
    }
    bar_lgkm();
    // bounce: 4x4 transpose blocks nat -> pT (b64 both sides, conflict-light)
#pragma unroll
    for (int kk = 0; kk < 4; ++kk) {
      const int w0 = (wb0 + kk * 32) * 4;
      bf4 rd0, rd1, rd2, rd3;
      {
        const int c0 = cb * 4;
        const int hfb = (w0 >> 8) * 512;
        const int ib2 = (w0 & 255) * 2;
        rd0 = *(const bf4*)(nat + (c0    ) * 1024 + hfb + (ib2 ^ (((c0    ) & 31) << 4)));
        rd1 = *(const bf4*)(nat + (c0 + 1) * 1024 + hfb + (ib2 ^ (((c0 + 1) & 31) << 4)));
        rd2 = *(const bf4*)(nat + (c0 + 2) * 1024 + hfb + (ib2 ^ (((c0 + 2) & 31) << 4)));
        rd3 = *(const bf4*)(nat + (c0 + 3) * 1024 + hfb + (ib2 ^ (((c0 + 3) & 31) << 4)));
      }
#pragma unroll
      for (int jj = 0; jj < 4; ++jj) {
        bf4 wv;
        wv[0] = rd0[jj]; wv[1] = rd1[jj]; wv[2] = rd2[jj]; wv[3] = rd3[jj];
        *(bf4*)(pT + (size_t)(w0 + jj) * 144 + cb * 8) = wv;
      }
    }
    bar_lgkm();
    // MFMA + store: O[c][i] for this wave's patch
#pragma unroll
    for (int ib = 0; ib < 2; ++ib) {
      f32x16 o0, o1;
#pragma unroll
      for (int i = 0; i < 16; ++i) { o0[i] = 0.f; o1[i] = 0.f; }
      const char* prow = pT + (size_t)(pc * 64 + ib * 32 + l31) * 144;
#pragma unroll
      for (int ks = 0; ks < 4; ++ks) {
        const bf8 pa = *(const bf8*)(prow + ks * 32 + hh * 16);
        o0 = MFMA(pa, af0[ks], o0, 0, 0, 0);
        o1 = MFMA(pa, af1[ks], o1, 0, 0, 0);
      }
#pragma unroll
      for (int rq = 0; rq < 4; ++rq) {
        const int wloc = pc * 64 + ib * 32 + rq * 8 + hh * 4;
        float* orow = ob + (size_t)r * NW + wloc;
        float4 q0; q0.x=o0[rq*4+0]; q0.y=o0[rq*4+1]; q0.z=o0[rq*4+2]; q0.w=o0[rq*4+3];
        *(float4*)(orow + (size_t)l31 * HWs) = q0;
        float4 q1; q1.x=o1[rq*4+0]; q1.y=o1[rq*4+1]; q1.z=o1[rq*4+2]; q1.w=o1[rq*4+3];
        *(float4*)(orow + (size_t)(32 + l31) * HWs) = q1;
      }
    }
    bar_lgkm();
  }
}

// ======================= fallback: R4 monolithic (proven) =======================
#define NS1 16
#define NS3 16

__device__ __forceinline__ void fb_load1(const float* g1, int st, float4 (&R)[16]) {
  const float* gp = g1 + (size_t)st * 4 * NW;
#pragma unroll
  for (int rl = 0; rl < 4; ++rl)
#pragma unroll
    for (int j = 0; j < 4; ++j)
      R[rl * 4 + j] = *(const float4*)(gp + (size_t)rl * NW + j * 4);
}
__device__ __forceinline__ void fb_cvtw1(char* wH, char* wL, int q_ld, int swzw,
                                         const float4 (&R)[16]) {
#pragma unroll
  for (int rl = 0; rl < 4; ++rl)
#pragma unroll
    for (int s = 0; s < 2; ++s) {
      const float4 va = R[rl * 4 + s * 2], vb = R[rl * 4 + s * 2 + 1];
      const float f[8] = {va.x, va.y, va.z, va.w, vb.x, vb.y, vb.z, vb.w};
      bf8 h, lo;
#pragma unroll
      for (int e = 0; e < 8; ++e) { h[e] = (__bf16)f[e]; lo[e] = (__bf16)(f[e] - (float)h[e]); }
      const int boff = (rl * 128 + q_ld * 32 + s * 16) ^ swzw;
      *(bf8*)(wH + boff) = h;
      *(bf8*)(wL + boff) = lo;
    }
}
__device__ __forceinline__ void fb_load3(const float* g3, int st, float4 (&R)[16]) {
  const float* gp = g3 + (size_t)st * 4 * NW;
#pragma unroll
  for (int cc = 0; cc < 4; ++cc)
#pragma unroll
    for (int j = 0; j < 4; ++j)
      R[cc * 4 + j] = *(const float4*)(gp + (size_t)cc * HWs + j * 4);
}
__device__ __forceinline__ void fb_cvtw3(char* sT, int cg, int iq, const float4 (&R)[16]) {
#pragma unroll
  for (int w = 0; w < 16; ++w) {
    bf4 q;
#pragma unroll
    for (int cc = 0; cc < 4; ++cc) q[cc] = (__bf16)F4E(R[cc * 4 + (w >> 2)], w & 3);
    const int iloc = iq * 16 + w;
    const int sw = ((iloc & 15) ^ ((iloc >> 4) & 7)) << 4;
    const int boff = (iloc & 127) * 256 + ((((iloc >> 7) << 7) + cg * 8) ^ sw);
    *(bf4*)(sT + boff) = q;
  }
}
extern "C" __global__ __launch_bounds__(256, 2)
void spectralAgg_fallback(const float* __restrict__ x, const float* __restrict__ g,
                          float* __restrict__ out) {
  __shared__ char lds[73728];
  char* sH = lds;
  char* sL = lds + 32768;
  char* sA = lds + 65536;
  const int t = threadIdx.x, wv = t >> 6, l = t & 63, l31 = l & 31, hh = l >> 5;
  const int wg = blockIdx.x, b = wg >> 6, pp = wg & 63, pr = pp >> 3, pcq = pp & 7;
  const size_t pbase = (size_t)b*64*HWs + (size_t)(pr*64)*NW + (size_t)(pcq*64);
  const float* xp = x + pbase;
  float* op = out + pbase;
  const int c_ld = t >> 2, q_ld = t & 3;
  const float* g1 = xp + (size_t)c_ld * HWs + q_ld * 16;
  char* wH = sH + c_ld * 512;
  char* wL = sL + c_ld * 512;
  const int swzw = (c_ld & 31) << 4;
  const int ct = wv >> 1, dt = wv & 1;
  const char* pA  = sH + (size_t)(ct*32+l31)*512;
  const char* pBh = sH + (size_t)(dt*32+l31)*512;
  const char* pBl = sL + (size_t)(dt*32+l31)*512;
  const int swzr = l31 << 4;
  f32x16 accG, accS;
#pragma unroll
  for (int i = 0; i < 16; ++i) { accG[i] = 0.f; accS[i] = 0.f; }
  float4 ra[16], rb[16];
  fb_load1(g1, 0, ra);
  for (int st = 0; st < NS1; ++st) {
    fb_load1(g1, (st + 1 < NS1) ? st + 1 : st, rb);
    fb_cvtw1(wH, wL, q_ld, swzw, ra);
    bar_lgkm();
#pragma unroll
    for (int k0 = 0; k0 < 16; ++k0) {
      const int off = (k0 * 32 + hh * 16) ^ swzr;
      const bf8 a  = *(const bf8*)(pA + off);
      const bf8 bh = *(const bf8*)(pBh + off);
      const bf8 bl = *(const bf8*)(pBl + off);
      accG = MFMA(a, bh, accG, 0, 0, 0);
      accS = MFMA(a, bl, accS, 0, 0, 0);
    }
    bar_lgkm();
#pragma unroll
    for (int e = 0; e < 16; ++e) ra[e] = rb[e];
  }
  float* S_lds = (float*)sL;
  float* E_lds = (float*)sH;
#pragma unroll
  for (int i = 0; i < 16; ++i) {
    const int cr = ct*32 + (i&3) + ((i>>2)<<3) + (hh<<2);
    S_lds[cr*64 + dt*32 + l31] = accS[i];
  }
  bar_lgkm();
#pragma unroll
  for (int i = 0; i < 16; ++i) {
    const int cr = ct*32 + (i&3) + ((i>>2)<<3) + (hh<<2);
    const int d = dt*32 + l31;
    E_lds[cr*64 + d] = accG[i] + accS[i] + S_lds[d*64 + cr];
  }
  bar_lgkm();
  const int cg = t >> 4, iq = t & 15;
  const float* g3 = xp + (size_t)(cg*4)*HWs + (size_t)(iq>>2)*NW + (iq&3)*16;
  fb_load3(g3, 0, ra);
  const float gs = 1.0f + g[0];
#pragma unroll 1
  for (int rr = 0; rr < 16; ++rr) {
    const int c = wv*16 + rr;
    const float e = E_lds[c*64 + l];
    float mn = e;
#pragma unroll
    for (int o = 32; o; o >>= 1) mn = fminf(mn, __shfl_xor(mn, o));
    const float w = __expf(mn - e);
    float s = w;
#pragma unroll
    for (int o = 32; o; o >>= 1) s += __shfl_xor(s, o);
    *(__bf16*)(sA + c*128 + ((l*2) ^ ((c&7)<<4))) = (__bf16)(gs * w / s);
  }
  bar_lgkm();
  bf8 bfr[2][4];
#pragma unroll
  for (int c2 = 0; c2 < 2; ++c2)
#pragma unroll
    for (int k0 = 0; k0 < 4; ++k0)
      bfr[c2][k0] = *(const bf8*)(sA + (size_t)(c2*32+l31)*128 +
                                  ((k0*32 + hh*16) ^ ((l31&7)<<4)));
  for (int st = 0; st < NS3; ++st) {
    fb_load3(g3, (st + 1 < NS3) ? st + 1 : st, rb);
    fb_cvtw3(sH, cg, iq, ra);
    bar_lgkm();
    f32x16 oo0[2], oo1[2];
#pragma unroll
    for (int it = 0; it < 2; ++it)
#pragma unroll
      for (int i = 0; i < 16; ++i) { oo0[it][i] = 0.f; oo1[it][i] = 0.f; }
#pragma unroll
    for (int it = 0; it < 2; ++it) {
      const int i = wv*64 + it*32 + l31;
      const char* base = sH + (size_t)(i & 127) * 256;
      const int hb = (i >> 7) * 128;
      const int sw = ((i & 15) ^ ((i >> 4) & 7)) << 4;
#pragma unroll
      for (int k0 = 0; k0 < 4; ++k0) {
        const bf8 pa = *(const bf8*)(base + ((hb + k0*32 + hh*16) ^ sw));
        oo0[it] = MFMA(pa, bfr[0][k0], oo0[it], 0, 0, 0);
        oo1[it] = MFMA(pa, bfr[1][k0], oo1[it], 0, 0, 0);
      }
    }
#pragma unroll
    for (int it = 0; it < 2; ++it)
#pragma unroll
      for (int rq = 0; rq < 4; ++rq) {
        const int iloc = wv*64 + it*32 + rq*8 + hh*4;
        const int gi = st*256 + iloc;
        float* oprow = op + (size_t)(gi >> 6)*NW + (gi & 63);
        float4 q0; q0.x=oo0[it][rq*4+0]; q0.y=oo0[it][rq*4+1]; q0.z=oo0[it][rq*4+2]; q0.w=oo0[it][rq*4+3];
        *(float4*)(oprow + (size_t)l31*HWs) = q0;
        float4 q1; q1.x=oo1[it][rq*4+0]; q1.y=oo1[it][rq*4+1]; q1.z=oo1[it][rq*4+2]; q1.w=oo1[it][rq*4+3];
        *(float4*)(oprow + (size_t)(32+l31)*HWs) = q1;
      }
    bar_lgkm();
#pragma unroll
    for (int e = 0; e < 16; ++e) ra[e] = rb[e];
  }
}

extern "C" void kernel_launch(void* const* d_in, const int* in_sizes, int n_in,
                              void* d_out, int out_size, void* d_ws, size_t ws_size,
                              hipStream_t stream) {
  const float* x = (const float*)d_in[0];
  const float* g = (const float*)d_in[1];
  float* o = (float*)d_out;
  const size_t need = (size_t)512 * 4 * 4096 * 4 + (size_t)512 * 4096 * 2; // 36MB
  if (ws_size >= need) {
    float* ep = (float*)d_ws;
    __bf16* attn = (__bf16*)((char*)d_ws + (size_t)512 * 4 * 4096 * 4);
    k1_gram<<<dim3(256), dim3(512), 0, stream>>>(x, ep);
    k2_softmax<<<dim3(512), dim3(256), 0, stream>>>(ep, g, attn);
    k3_pv<<<dim3(256), dim3(512), 0, stream>>>(x, attn, o);
  } else {
    spectralAgg_fallback<<<dim3(512), dim3(256), 0, stream>>>(x, g, o);
  }
}